// Round 2
// baseline (4393.206 us; speedup 1.0000x reference)
//
#include <hip/hip_runtime.h>

constexpr int N = 50000;
constexpr int E = 800000;
constexpr int D = 128;
constexpr int MASKN = 25000;
constexpr int SCAN_CHUNK = 1024;
constexpr int NB_SCAN = (N + SCAN_CHUNK - 1) / SCAN_CHUNK; // 49

#define FMA4(acc, s, b)                                                        \
    acc.x = fmaf(s, b.x, acc.x);                                               \
    acc.y = fmaf(s, b.y, acc.y);                                               \
    acc.z = fmaf(s, b.z, acc.z);                                               \
    acc.w = fmaf(s, b.w, acc.w)

#define ADD4(acc, v)                                                           \
    acc.x += v.x;                                                              \
    acc.y += v.y;                                                              \
    acc.z += v.z;                                                              \
    acc.w += v.w

// ---------------- CSR build ----------------

__global__ void k_count(const int* __restrict__ src, const int* __restrict__ dst,
                        int* __restrict__ cnt_src, int* __restrict__ cnt_dst) {
    int e = blockIdx.x * blockDim.x + threadIdx.x;
    if (e < E) {
        atomicAdd(&cnt_src[src[e]], 1);
        atomicAdd(&cnt_dst[dst[e]], 1);
    }
}

__global__ void k_scan1(const int* __restrict__ cnt, int* __restrict__ bsum) {
    __shared__ int sh[256];
    int base = blockIdx.x * SCAN_CHUNK;
    int t = threadIdx.x;
    int s = 0;
#pragma unroll
    for (int j = 0; j < 4; ++j) {
        int i = base + t * 4 + j;
        if (i < N) s += cnt[i];
    }
    sh[t] = s;
    __syncthreads();
    for (int o = 128; o > 0; o >>= 1) {
        if (t < o) sh[t] += sh[t + o];
        __syncthreads();
    }
    if (t == 0) bsum[blockIdx.x] = sh[0];
}

__global__ void k_scan2(int* __restrict__ bsum, int* __restrict__ row_ptr) {
    if (threadIdx.x == 0 && blockIdx.x == 0) {
        int run = 0;
        for (int i = 0; i < NB_SCAN; ++i) {
            int v = bsum[i];
            bsum[i] = run;
            run += v;
        }
        row_ptr[N] = run; // == E
    }
}

__global__ void k_scan3(const int* __restrict__ cnt, const int* __restrict__ bsum,
                        int* __restrict__ row_ptr) {
    __shared__ int sh[256];
    int base = blockIdx.x * SCAN_CHUNK;
    int t = threadIdx.x;
    int v[4];
    int tot = 0;
#pragma unroll
    for (int j = 0; j < 4; ++j) {
        int i = base + t * 4 + j;
        v[j] = (i < N) ? cnt[i] : 0;
        tot += v[j];
    }
    sh[t] = tot;
    __syncthreads();
    for (int o = 1; o < 256; o <<= 1) {
        int y = (t >= o) ? sh[t - o] : 0;
        __syncthreads();
        sh[t] += y;
        __syncthreads();
    }
    int excl = sh[t] - tot;
    int off = bsum[blockIdx.x] + excl;
    int run = 0;
#pragma unroll
    for (int j = 0; j < 4; ++j) {
        int i = base + t * 4 + j;
        if (i < N) row_ptr[i] = off + run;
        run += v[j];
    }
}

__global__ void k_fill(const int* __restrict__ src, const int* __restrict__ dst,
                       const int* __restrict__ row_ptr, int* __restrict__ cursor,
                       int* __restrict__ col) {
    int e = blockIdx.x * blockDim.x + threadIdx.x;
    if (e < E) {
        int d = dst[e];
        int p = row_ptr[d] + atomicAdd(&cursor[d], 1);
        col[p] = src[e];
    }
}

__global__ void k_dinv(const int* __restrict__ cs, const int* __restrict__ cd,
                       float* __restrict__ dinv_out, float* __restrict__ dinv_in) {
    int i = blockIdx.x * blockDim.x + threadIdx.x;
    if (i < N) {
        int a = cs[i] > 1 ? cs[i] : 1;
        int b = cd[i] > 1 ? cd[i] : 1;
        dinv_out[i] = rsqrtf((float)a);
        dinv_in[i] = rsqrtf((float)b);
    }
}

__global__ void k_mflag(const int* __restrict__ mask_nodes, int* __restrict__ mflag) {
    int i = blockIdx.x * blockDim.x + threadIdx.x;
    if (i < MASKN) mflag[mask_nodes[i]] = 1;
}

// ---------------- feature prep: masked x scaled by deg_out^-0.5 ----------------

__global__ void k_prep(const float4* __restrict__ x, const float4* __restrict__ tok,
                       const int* __restrict__ mflag, const float* __restrict__ dinv_out,
                       float4* __restrict__ A) {
    int i = blockIdx.x * blockDim.x + threadIdx.x; // over N*32 float4s
    if (i < N * 32) {
        int row = i >> 5;
        int c = i & 31;
        float s = dinv_out[row];
        float4 v = mflag[row] ? tok[c] : x[i];
        A[i] = make_float4(v.x * s, v.y * s, v.z * s, v.w * s);
    }
}

// ---------------- SpMM: B[row] = sum over CSR neighbors of A[col] ----------------
// one wave per row; half-wave (32 lanes x float4) covers the 512B row, so each
// vector instruction gathers TWO edges; 8-edge unroll keeps 4 gathers in flight.

__global__ void k_spmm(const float4* __restrict__ A4, float4* __restrict__ B4,
                       const int* __restrict__ row_ptr, const int* __restrict__ col,
                       const int* __restrict__ rows, int nrows) {
    int rr = blockIdx.x * blockDim.y + threadIdx.y;
    if (rr >= nrows) return;
    int row = rows ? rows[rr] : rr;
    int lane = threadIdx.x;
    int half = lane >> 5;
    int j = lane & 31;
    int beg = row_ptr[row], end = row_ptr[row + 1];
    float4 acc = make_float4(0.f, 0.f, 0.f, 0.f);
    float4 acc2 = make_float4(0.f, 0.f, 0.f, 0.f);
    int e = beg;
    for (; e + 8 <= end; e += 8) {
        int c0 = col[e + half];
        int c1 = col[e + 2 + half];
        int c2 = col[e + 4 + half];
        int c3 = col[e + 6 + half];
        float4 v0 = A4[(size_t)c0 * 32 + j];
        float4 v1 = A4[(size_t)c1 * 32 + j];
        float4 v2 = A4[(size_t)c2 * 32 + j];
        float4 v3 = A4[(size_t)c3 * 32 + j];
        ADD4(acc, v0);
        ADD4(acc2, v1);
        ADD4(acc, v2);
        ADD4(acc2, v3);
    }
    for (; e + 2 <= end; e += 2) {
        int c = col[e + half];
        float4 v = A4[(size_t)c * 32 + j];
        ADD4(acc, v);
    }
    if (e < end && half == 0) {
        int c = col[e];
        float4 v = A4[(size_t)c * 32 + j];
        ADD4(acc, v);
    }
    ADD4(acc, acc2);
    acc.x += __shfl_xor(acc.x, 32);
    acc.y += __shfl_xor(acc.y, 32);
    acc.z += __shfl_xor(acc.z, 32);
    acc.w += __shfl_xor(acc.w, 32);
    if (half == 0) B4[(size_t)row * 32 + j] = acc;
}

// ---------------- dense GEMM core ----------------
// 256 threads, 32-row tile, 128 cols. tx = t&31 owns cols 4tx..4tx+3,
// ty = t>>5 owns rows ty*4..ty*4+3 of the tile -> each row's 128 outputs live
// entirely in one 32-lane half-wave (LN via shuffles, no LDS).
// W^T staged in LDS in two 32KB k-halves: 48KB total -> 3 blocks/CU.

__device__ __forceinline__ void gemm_tile(const float* __restrict__ sh_in,
                                          float* __restrict__ sh_w,
                                          const float4* __restrict__ W4, int tx,
                                          int ty, int t, float4 acc[4]) {
#pragma unroll
    for (int kh = 0; kh < 2; ++kh) {
        __syncthreads();
        // stage W^T half: Wt[k][o] for k in [64*kh, 64*kh+64)
#pragma unroll
        for (int jj = 0; jj < 8; ++jj) {
            int fidx = t * 8 + jj; // 0..2047
            int o = fidx >> 4, kq = fidx & 15;
            float4 wv = W4[o * 32 + kh * 16 + kq];
            sh_w[(4 * kq + 0) * 128 + o] = wv.x;
            sh_w[(4 * kq + 1) * 128 + o] = wv.y;
            sh_w[(4 * kq + 2) * 128 + o] = wv.z;
            sh_w[(4 * kq + 3) * 128 + o] = wv.w;
        }
        __syncthreads();
        const float4* shw4 = (const float4*)sh_w;
        const float4* shi4 = (const float4*)sh_in;
#pragma unroll
        for (int k4 = 0; k4 < 16; ++k4) {
            float4 b0 = shw4[(4 * k4 + 0) * 32 + tx];
            float4 b1 = shw4[(4 * k4 + 1) * 32 + tx];
            float4 b2 = shw4[(4 * k4 + 2) * 32 + tx];
            float4 b3 = shw4[(4 * k4 + 3) * 32 + tx];
#pragma unroll
            for (int rr = 0; rr < 4; ++rr) {
                float4 a = shi4[(ty * 4 + rr) * 32 + kh * 16 + k4];
                FMA4(acc[rr], a.x, b0);
                FMA4(acc[rr], a.y, b1);
                FMA4(acc[rr], a.z, b2);
                FMA4(acc[rr], a.w, b3);
            }
        }
    }
}

template <bool LN, bool SCALE_OUT, bool MASK_ZERO>
__launch_bounds__(256, 3) __global__
void k_dense(const float4* __restrict__ in, float4* __restrict__ out,
             const float4* __restrict__ W4, const float4* __restrict__ bias4,
             const float4* __restrict__ g4, const float4* __restrict__ be4,
             const float* __restrict__ aP, const float* __restrict__ dinv_in,
             const float* __restrict__ dinv_out, const int* __restrict__ mflag) {
    __shared__ float sh_in[32 * 128];
    __shared__ float sh_w[64 * 128];
    int t = threadIdx.x;
    int tx = t & 31, ty = t >> 5;
    int rbase = blockIdx.x * 32;
    {
        const float4* inb = in + (size_t)rbase * 32;
        float4* shi4 = (float4*)sh_in;
        int maxf = (N - rbase) * 32;
#pragma unroll
        for (int jj = 0; jj < 4; ++jj) {
            int fidx = t + 256 * jj;
            int s = fidx < maxf ? fidx : 0;
            shi4[fidx] = inb[s];
        }
    }
    float4 acc[4];
#pragma unroll
    for (int rr = 0; rr < 4; ++rr) acc[rr] = make_float4(0.f, 0.f, 0.f, 0.f);
    gemm_tile(sh_in, sh_w, W4, tx, ty, t, acc);

    float alpha = 0.f;
    float4 bb = make_float4(0.f, 0.f, 0.f, 0.f), gg = bb, ee = bb;
    if constexpr (LN) {
        alpha = aP[0];
        bb = bias4[tx];
        gg = g4[tx];
        ee = be4[tx];
    }
#pragma unroll
    for (int rr = 0; rr < 4; ++rr) {
        int row = rbase + ty * 4 + rr;
        if (row < N) {
            float4 v = acc[rr];
            if constexpr (LN) {
                float di = dinv_in[row];
                v.x = (v.x + bb.x) * di;
                v.y = (v.y + bb.y) * di;
                v.z = (v.z + bb.z) * di;
                v.w = (v.w + bb.w) * di;
                float s = v.x + v.y + v.z + v.w;
                float q = v.x * v.x + v.y * v.y + v.z * v.z + v.w * v.w;
#pragma unroll
                for (int o = 16; o > 0; o >>= 1) {
                    s += __shfl_xor(s, o);
                    q += __shfl_xor(q, o);
                }
                float mu = s * (1.f / D);
                float var = q * (1.f / D) - mu * mu;
                float rs = rsqrtf(var + 1e-5f);
                v.x = (v.x - mu) * rs * gg.x + ee.x;
                v.y = (v.y - mu) * rs * gg.y + ee.y;
                v.z = (v.z - mu) * rs * gg.z + ee.z;
                v.w = (v.w - mu) * rs * gg.w + ee.w;
                v.x = v.x >= 0.f ? v.x : alpha * v.x;
                v.y = v.y >= 0.f ? v.y : alpha * v.y;
                v.z = v.z >= 0.f ? v.z : alpha * v.z;
                v.w = v.w >= 0.f ? v.w : alpha * v.w;
            }
            if (MASK_ZERO && mflag[row]) v = make_float4(0.f, 0.f, 0.f, 0.f);
            if constexpr (SCALE_OUT) {
                float so = dinv_out[row];
                v.x *= so;
                v.y *= so;
                v.z *= so;
                v.w *= so;
            }
            out[(size_t)row * 32 + tx] = v;
        }
    }
}

// decoder fc + degnorm + SCE loss over masked rows (same GEMM core)
__launch_bounds__(256, 3) __global__
void k_loss(const float4* __restrict__ agg4, const float4* __restrict__ x4,
            const float4* __restrict__ Wd4, const float4* __restrict__ bd4,
            const float* __restrict__ dinv_in, const int* __restrict__ mask_nodes,
            float* __restrict__ outp) {
    __shared__ float sh_in[32 * 128];
    __shared__ float sh_w[64 * 128];
    __shared__ int sh_rows[32];
    __shared__ float sh_acc;
    int t = threadIdx.x;
    int tx = t & 31, ty = t >> 5;
    int base = blockIdx.x * 32;
    if (t < 32) {
        int idx = base + t;
        sh_rows[t] = idx < MASKN ? mask_nodes[idx] : -1;
    }
    if (t == 0) sh_acc = 0.f;
    __syncthreads();
    {
        float4* shi4 = (float4*)sh_in;
#pragma unroll
        for (int jj = 0; jj < 4; ++jj) {
            int fidx = t + 256 * jj;
            int rl = fidx >> 5, kq = fidx & 31;
            int m = sh_rows[rl];
            shi4[fidx] = (m >= 0) ? agg4[(size_t)m * 32 + kq]
                                  : make_float4(0.f, 0.f, 0.f, 0.f);
        }
    }
    float4 acc[4];
#pragma unroll
    for (int rr = 0; rr < 4; ++rr) acc[rr] = make_float4(0.f, 0.f, 0.f, 0.f);
    gemm_tile(sh_in, sh_w, Wd4, tx, ty, t, acc);

    float4 bb = bd4[tx];
    float lsum = 0.f;
#pragma unroll
    for (int rr = 0; rr < 4; ++rr) {
        int m = sh_rows[ty * 4 + rr];
        if (m >= 0) {
            float di = dinv_in[m];
            float4 r;
            r.x = (acc[rr].x + bb.x) * di;
            r.y = (acc[rr].y + bb.y) * di;
            r.z = (acc[rr].z + bb.z) * di;
            r.w = (acc[rr].w + bb.w) * di;
            float4 xv = x4[(size_t)m * 32 + tx];
            float a = r.x * r.x + r.y * r.y + r.z * r.z + r.w * r.w;
            float b = xv.x * xv.x + xv.y * xv.y + xv.z * xv.z + xv.w * xv.w;
            float c = r.x * xv.x + r.y * xv.y + r.z * xv.z + r.w * xv.w;
#pragma unroll
            for (int o = 16; o > 0; o >>= 1) {
                a += __shfl_xor(a, o);
                b += __shfl_xor(b, o);
                c += __shfl_xor(c, o);
            }
            if (tx == 0) {
                float nr = fmaxf(sqrtf(a), 1e-12f);
                float nx = fmaxf(sqrtf(b), 1e-12f);
                float term = 1.f - c / (nr * nx);
                lsum += term * term;
            }
        }
    }
    if (tx == 0) atomicAdd(&sh_acc, lsum);
    __syncthreads();
    if (t == 0) atomicAdd(outp, sh_acc * (1.f / MASKN));
}

// ---------------- launch ----------------

extern "C" void kernel_launch(void* const* d_in, const int* in_sizes, int n_in,
                              void* d_out, int out_size, void* d_ws, size_t ws_size,
                              hipStream_t stream) {
    const float* x = (const float*)d_in[0];
    const float* tok = (const float*)d_in[1];
    const float* W1 = (const float*)d_in[2];
    const float* b1 = (const float*)d_in[3];
    const float* g1 = (const float*)d_in[4];
    const float* be1 = (const float*)d_in[5];
    const float* a1 = (const float*)d_in[6];
    const float* W2 = (const float*)d_in[7];
    const float* b2 = (const float*)d_in[8];
    const float* g2 = (const float*)d_in[9];
    const float* be2 = (const float*)d_in[10];
    const float* a2 = (const float*)d_in[11];
    const float* We2d = (const float*)d_in[12];
    const float* Wd = (const float*)d_in[13];
    const float* bd = (const float*)d_in[14];
    const int* src = (const int*)d_in[15];
    const int* dst = (const int*)d_in[16];
    const int* mask_nodes = (const int*)d_in[17];

    char* w = (char*)d_ws;
    float* A = (float*)w;       w += (size_t)N * D * 4;
    float* Bf = (float*)w;      w += (size_t)N * D * 4;
    int* col = (int*)w;         w += (size_t)E * 4;
    int* row_ptr = (int*)w;     w += (size_t)(N + 1) * 4;
    int* cnt_src = (int*)w;     w += (size_t)N * 4;
    int* cnt_dst = (int*)w;     w += (size_t)N * 4;
    int* cursor = (int*)w;      w += (size_t)N * 4;
    int* mflag = (int*)w;       w += (size_t)N * 4;
    int* bsum = (int*)w;        w += 256 * 4;
    float* dinv_out = (float*)w; w += (size_t)N * 4;
    float* dinv_in = (float*)w;  w += (size_t)N * 4;

    // zero: cnt_src, cnt_dst, cursor, mflag (contiguous 4*N ints) + output scalar
    hipMemsetAsync(cnt_src, 0, (size_t)4 * N * 4, stream);
    hipMemsetAsync(d_out, 0, sizeof(float), stream);

    k_count<<<(E + 255) / 256, 256, 0, stream>>>(src, dst, cnt_src, cnt_dst);
    k_scan1<<<NB_SCAN, 256, 0, stream>>>(cnt_dst, bsum);
    k_scan2<<<1, 64, 0, stream>>>(bsum, row_ptr);
    k_scan3<<<NB_SCAN, 256, 0, stream>>>(cnt_dst, bsum, row_ptr);
    k_fill<<<(E + 255) / 256, 256, 0, stream>>>(src, dst, row_ptr, cursor, col);
    k_dinv<<<(N + 255) / 256, 256, 0, stream>>>(cnt_src, cnt_dst, dinv_out, dinv_in);
    k_mflag<<<(MASKN + 255) / 256, 256, 0, stream>>>(mask_nodes, mflag);
    k_prep<<<(N * 32 + 255) / 256, 256, 0, stream>>>((const float4*)x, (const float4*)tok,
                                                     mflag, dinv_out, (float4*)A);
    dim3 bs(64, 4);
    int ndense = (N + 31) / 32;
    int nloss = (MASKN + 31) / 32;
    // conv1: agg
    k_spmm<<<(N + 3) / 4, bs, 0, stream>>>((const float4*)A, (float4*)Bf, row_ptr, col, nullptr, N);
    // conv1 epilogue: fc + in-deg norm + LN + PReLU, pre-scale by deg_out^-0.5
    k_dense<true, true, false><<<ndense, 256, 0, stream>>>(
        (const float4*)Bf, (float4*)A, (const float4*)W1, (const float4*)b1,
        (const float4*)g1, (const float4*)be1, a1, dinv_in, dinv_out, nullptr);
    // conv2: agg
    k_spmm<<<(N + 3) / 4, bs, 0, stream>>>((const float4*)A, (float4*)Bf, row_ptr, col, nullptr, N);
    // conv2 epilogue: h2 (unscaled)
    k_dense<true, false, false><<<ndense, 256, 0, stream>>>(
        (const float4*)Bf, (float4*)A, (const float4*)W2, (const float4*)b2,
        (const float4*)g2, (const float4*)be2, a2, dinv_in, dinv_out, nullptr);
    // encoder_to_decoder + re-mask + pre-scale for conv3
    k_dense<false, true, true><<<ndense, 256, 0, stream>>>(
        (const float4*)A, (float4*)Bf, (const float4*)We2d, nullptr, nullptr,
        nullptr, nullptr, dinv_in, dinv_out, mflag);
    // conv3: agg, masked rows only
    k_spmm<<<(MASKN + 3) / 4, bs, 0, stream>>>((const float4*)Bf, (float4*)A, row_ptr, col,
                                               mask_nodes, MASKN);
    // decoder fc + SCE loss
    k_loss<<<nloss, 256, 0, stream>>>((const float4*)A, (const float4*)x,
                                      (const float4*)Wd, (const float4*)bd,
                                      dinv_in, mask_nodes, (float*)d_out);
}